// Round 1
// 4347.503 us; speedup vs baseline: 1.0700x; 1.0700x over previous
//
#include <hip/hip_runtime.h>
#include <stdint.h>

// ---------------------------------------------------------------------------
// DecoderRnn: 2-layer LSTM (B=32, H=512) over T=64 steps + vocab softmax (V=32000)
//   K1 k_init  : zero h2 double-buffer, rowsum, barrier flags
//   K2 k_wcvt  : W_out f32 -> bf16 for MFMA
//   K3 k_xg1   : Xg1T[t][j][b] = emb(x_t)@W_ih1^T + b_ih1 + b_hh1   (f32)
//   K4 k_serial: 64-step recurrence, 256 persistent WGs (1/CU).
//                Cross-WG h exchange via relaxed agent-scope u64 atomics
//                (L3-coherent, no cache-flush fences). Barrier = per-WG flag
//                array: RELAXED-store post (round-2 fix: a RELEASE store at
//                agent scope emits buffer_wbl2 = full L2 writeback walk on
//                gfx950 -> ~50us/step serialized across 32 WGs/XCD. The
//                __syncthreads() before the post already drains vmcnt(0) in
//                every wave, and all h-state stores are sc1 atomics that
//                complete at the coherence point, so ordering holds without
//                the wbl2). Relaxed polls (NO buffer_inv in the spin loop —
//                round-1's 53us/sync bug).
//                Gate combine via in-wave shuffles; 2 LDS stages/step.
//   K5 k_vocab : unnormalized probs = exp(H2@W_out^T + b_out), bf16 MFMA
//   K6 k_scale : probs /= rowsum
// ---------------------------------------------------------------------------

constexpr int kH = 512;
constexpr int kB = 32;
constexpr int kT = 64;
constexpr int kV = 32000;
constexpr int kG = 2048;   // 4*kH gates
constexpr int kNWG = 256;  // serial-kernel workgroups (1 per CU)

typedef __attribute__((ext_vector_type(4))) float f4;
typedef __attribute__((ext_vector_type(8))) short short8;
typedef unsigned long long u64;

struct us4 { unsigned short x, y, z, w; };

__device__ inline unsigned short f2bf(float x) {
  union { float f; unsigned u; } c; c.f = x;
  unsigned r = c.u + 0x7fffu + ((c.u >> 16) & 1u);   // RNE to bf16
  return (unsigned short)(r >> 16);
}
__device__ inline float sigm(float x) { return 1.0f / (1.0f + expf(-x)); }

// ---------------------------------------------------------------------- K1
__global__ void k_init(float* __restrict__ buf2, float* __restrict__ rowsum,
                       int* __restrict__ flags /* 512 ints: A then B */) {
  int id = blockIdx.x * 256 + threadIdx.x;
  f4 z = {0.f, 0.f, 0.f, 0.f};
  if (id < 8192) ((f4*)buf2)[id] = z;       // both h2 buffers = 0
  if (id < 2048) rowsum[id] = 0.f;
  if (id < 512)  flags[id] = 0;
}

// ---------------------------------------------------------------------- K2
__global__ void k_wcvt(const float* __restrict__ W, unsigned short* __restrict__ Wu) {
  const int total = kV * kH / 4;
  for (int i = blockIdx.x * blockDim.x + threadIdx.x; i < total;
       i += gridDim.x * blockDim.x) {
    f4 v = ((const f4*)W)[i];
    us4 o = {f2bf(v.x), f2bf(v.y), f2bf(v.z), f2bf(v.w)};
    ((us4*)Wu)[i] = o;
  }
}

// ---------------------------------------------------------------------- K3
__global__ __launch_bounds__(256) void k_xg1(
    const int* __restrict__ inputs, const int* __restrict__ tseq,
    const float* __restrict__ emb, const float* __restrict__ Wih1,
    const float* __restrict__ bih1, const float* __restrict__ bhh1,
    float* __restrict__ Xg1T) {
  __shared__ float Xs[kB * kH];   // 64 KiB
  int tid = threadIdx.x;
  int t = blockIdx.x, jb = blockIdx.y;
  for (int i = tid; i < kB * kH / 4; i += 256) {
    int b = i >> 7;
    int tok = (t == 0) ? inputs[b] : tseq[b * kT + (t - 1)];
    ((f4*)Xs)[i] = ((const f4*)(emb + (size_t)tok * kH))[i & 127];
  }
  __syncthreads();
  int j2 = tid & 31, bq = tid >> 5;
  int j0 = jb * 64 + j2 * 2;
  int b0 = bq * 4;
  const f4* w0 = (const f4*)(Wih1 + (size_t)j0 * kH);
  const f4* w1 = (const f4*)(Wih1 + (size_t)(j0 + 1) * kH);
  float acc0[4] = {0.f, 0.f, 0.f, 0.f};
  float acc1[4] = {0.f, 0.f, 0.f, 0.f};
  #pragma unroll 2
  for (int k4 = 0; k4 < 128; ++k4) {
    f4 a0 = w0[k4], a1 = w1[k4];
    #pragma unroll
    for (int bb = 0; bb < 4; ++bb) {
      f4 x = ((const f4*)Xs)[(b0 + bb) * 128 + k4];
      acc0[bb] += a0.x * x.x + a0.y * x.y + a0.z * x.z + a0.w * x.w;
      acc1[bb] += a1.x * x.x + a1.y * x.y + a1.z * x.z + a1.w * x.w;
    }
  }
  float bj0 = bih1[j0] + bhh1[j0];
  float bj1 = bih1[j0 + 1] + bhh1[j0 + 1];
  f4 s0 = {acc0[0] + bj0, acc0[1] + bj0, acc0[2] + bj0, acc0[3] + bj0};
  f4 s1 = {acc1[0] + bj1, acc1[1] + bj1, acc1[2] + bj1, acc1[3] + bj1};
  float* o = Xg1T + ((size_t)t * kG + j0) * kB + b0;
  *(f4*)o = s0;
  *(f4*)(o + kB) = s1;
}

// ---------------------------------------------------------------------- K4
// Barrier: post = RELAXED store of my flag. Ordering: __syncthreads() drains
// vmcnt(0) in every wave (all sc1 data stores complete at the coherence
// point) before thread 0 issues the flag store — no release needed, which
// avoids the agent-release buffer_wbl2 (full L2 writeback) on gfx950.
// wait = 256 threads poll 256 flags with RELAXED coherent loads.
__device__ inline void post(int* flags, int v) {
  __syncthreads();   // every wave drains vmcnt before s_barrier -> stores done
  if (threadIdx.x == 0)
    __hip_atomic_store(&flags[blockIdx.x], v, __ATOMIC_RELAXED,
                       __HIP_MEMORY_SCOPE_AGENT);
}
__device__ inline void waitf(int* flags, int v) {
  while (__hip_atomic_load(&flags[threadIdx.x], __ATOMIC_RELAXED,
                           __HIP_MEMORY_SCOPE_AGENT) < v)
    __builtin_amdgcn_s_sleep(2);
  __syncthreads();
}

// Stage 32x512 f32 h-state into LDS (f4 XOR-swizzle: the 8 b-rows a wave
// reads per ds_read_b128 land on disjoint bank quads). Coherent variant uses
// relaxed agent u64 loads (bypasses stale L1 / non-coherent per-XCD L2).
__device__ inline void stage_coh(float* __restrict__ smem, const float* src) {
  const u64* s8 = (const u64*)src;
  #pragma unroll
  for (int i = 0; i < 16; ++i) {
    int idx = threadIdx.x + (i << 8);          // f4 index 0..4095
    u64 lo = __hip_atomic_load((u64*)&s8[idx * 2], __ATOMIC_RELAXED,
                               __HIP_MEMORY_SCOPE_AGENT);
    u64 hi = __hip_atomic_load((u64*)&s8[idx * 2 + 1], __ATOMIC_RELAXED,
                               __HIP_MEMORY_SCOPE_AGENT);
    int b_ = idx >> 7, k4 = idx & 127;
    union { u64 u[2]; f4 v; } cv; cv.u[0] = lo; cv.u[1] = hi;
    ((f4*)smem)[(b_ << 7) + (k4 ^ (b_ & 7))] = cv.v;
  }
}
__device__ inline void stage_plain(float* __restrict__ smem,
                                   const float* __restrict__ src) {
  const f4* s4 = (const f4*)src;
  #pragma unroll
  for (int i = 0; i < 16; ++i) {
    int idx = threadIdx.x + (i << 8);
    int b_ = idx >> 7, k4 = idx & 127;
    ((f4*)smem)[(b_ << 7) + (k4 ^ (b_ & 7))] = s4[idx];
  }
}

__global__ __launch_bounds__(256) void k_serial(
    const float* __restrict__ hiddens, const float* __restrict__ Xg1T,
    const float* __restrict__ Whh1, const float* __restrict__ Wih2,
    const float* __restrict__ Whh2, const float* __restrict__ bih2,
    const float* __restrict__ bhh2,
    float* __restrict__ buf1, float* __restrict__ buf2,
    unsigned short* __restrict__ H2u, float* __restrict__ outTail,
    int* __restrict__ flagsA, int* __restrict__ flagsB) {
  __shared__ float smem[kB * kH];   // exactly 64 KiB
  const int tid = threadIdx.x, w = blockIdx.x;
  const int lane = tid & 63;
  const int b = tid >> 3, jj = tid & 7, gg = jj >> 1, nl = jj & 1;
  const int n = (w << 1) + nl;      // this WG owns hidden columns {2w, 2w+1}
  const int j = (gg << 9) + n;      // gate row: gate*512 + n
  const float bias2 = bih2[j] + bhh2[j];
  const f4* w1r = (const f4*)(Whh1 + (size_t)j * kH);
  const f4* w2a = (const f4*)(Wih2 + (size_t)j * kH);
  const f4* w2b = (const f4*)(Whh2 + (size_t)j * kH);
  const bool holder = (jj < 2);     // thread (b,nl) carries c-state for col n
  const int srcbase = (lane & 56) | (lane & 1);
  float c1 = 0.f, c2 = 0.f;
  const int boff = b << 7, bsw = b & 7;

  stage_plain(smem, hiddens);       // h1[-1]
  __syncthreads();
  for (int t = 0; t < kT; ++t) {
    float* h1w = buf1 + (t & 1) * 16384;
    float* h2w = buf2 + (t & 1) * 16384;
    const float* h2r = buf2 + ((t + 1) & 1) * 16384;   // h2[t-1]

    // ---- layer-1 gates: Whh1[j].h1[t-1] + Xg1T (x-term incl. biases) ----
    float xg = Xg1T[((size_t)t * kG + j) * kB + b];
    f4 acc = {0.f, 0.f, 0.f, 0.f};
    #pragma unroll 8
    for (int k4 = 0; k4 < 128; ++k4)
      acc += w1r[k4] * ((const f4*)smem)[boff + (k4 ^ bsw)];
    float g1v = acc.x + acc.y + acc.z + acc.w + xg;
    // in-wave gate combine (gates i,f,g,o for col n are at jj = nl,2+nl,4+nl,6+nl)
    float gi = __shfl(g1v, srcbase);
    float gf = __shfl(g1v, srcbase + 2);
    float gG = __shfl(g1v, srcbase + 4);
    float go = __shfl(g1v, srcbase + 6);
    float hnew = 0.f;
    if (holder) {
      float i_ = sigm(gi), f_ = sigm(gf), G_ = tanhf(gG), o_ = sigm(go);
      c1 = f_ * c1 + i_ * G_;
      hnew = o_ * tanhf(c1);
    }
    float hp = __shfl(hnew, lane + 1);
    if (jj == 0) {
      union { float f[2]; u64 u; } pk; pk.f[0] = hnew; pk.f[1] = hp;
      __hip_atomic_store((u64*)(h1w + b * kH + 2 * w), pk.u, __ATOMIC_RELAXED,
                         __HIP_MEMORY_SCOPE_AGENT);
      if (t == kT - 1) *(u64*)(outTail + b * kH + 2 * w) = pk.u;  // output 1
    }
    post(flagsA, t + 1);            // publish h1[t] (syncthreads drains stores)
    waitf(flagsB, t);               // h2[t-1] visible from all WGs

    stage_coh(smem, h2r);           // h2[t-1]
    __syncthreads();
    // ---- layer-2 partial: Whh2[j].h2[t-1] (overlaps other WGs' A-posts) ----
    f4 a2 = {0.f, 0.f, 0.f, 0.f};
    #pragma unroll 8
    for (int k4 = 0; k4 < 128; ++k4)
      a2 += w2b[k4] * ((const f4*)smem)[boff + (k4 ^ bsw)];
    waitf(flagsA, t + 1);           // h1[t] visible from all WGs

    stage_coh(smem, h1w);           // h1[t] (stays staged for next step's layer-1)
    __syncthreads();
    #pragma unroll 8
    for (int k4 = 0; k4 < 128; ++k4)
      a2 += w2a[k4] * ((const f4*)smem)[boff + (k4 ^ bsw)];
    float g2v = a2.x + a2.y + a2.z + a2.w + bias2;
    float g2i = __shfl(g2v, srcbase);
    float g2f = __shfl(g2v, srcbase + 2);
    float g2G = __shfl(g2v, srcbase + 4);
    float g2o = __shfl(g2v, srcbase + 6);
    float h2new = 0.f;
    if (holder) {
      float i_ = sigm(g2i), f_ = sigm(g2f), G_ = tanhf(g2G), o_ = sigm(g2o);
      c2 = f_ * c2 + i_ * G_;
      h2new = o_ * tanhf(c2);
    }
    float h2p = __shfl(h2new, lane + 1);
    if (jj == 0) {
      union { float f[2]; u64 u; } pk; pk.f[0] = h2new; pk.f[1] = h2p;
      __hip_atomic_store((u64*)(h2w + b * kH + 2 * w), pk.u, __ATOMIC_RELAXED,
                         __HIP_MEMORY_SCOPE_AGENT);
      unsigned bf2 = ((unsigned)f2bf(h2p) << 16) | f2bf(h2new);
      *(unsigned*)(H2u + ((size_t)t * kB + b) * kH + 2 * w) = bf2;  // bf16 pair
    }
    post(flagsB, t + 1);            // publish h2[t]
    // smem still holds h1[t] -> next iteration's layer-1 needs no restage
  }
}

// ---------------------------------------------------------------------- K5
__global__ __launch_bounds__(256) void k_vocab(
    const unsigned short* __restrict__ H2u, const unsigned short* __restrict__ Wu,
    const float* __restrict__ bout, float* __restrict__ out,
    float* __restrict__ rowsum) {
  const int lane = threadIdx.x & 63, wv = threadIdx.x >> 6;
  const int wm = wv >> 1, wn = wv & 1;
  const int r16 = lane & 15, quad = lane >> 4;
  const int mBase = blockIdx.y * 128 + wm * 64;
  const int nBase = blockIdx.x * 128 + wn * 64;
  f4 acc[4][4];
  #pragma unroll
  for (int a = 0; a < 4; ++a)
    #pragma unroll
    for (int c = 0; c < 4; ++c) acc[a][c] = (f4){0.f, 0.f, 0.f, 0.f};
  for (int kb = 0; kb < 16; ++kb) {
    int k0 = kb * 32 + quad * 8;
    short8 af[4], bf[4];
    #pragma unroll
    for (int mt = 0; mt < 4; ++mt)
      af[mt] = *(const short8*)(H2u + (size_t)(mBase + mt * 16 + r16) * kH + k0);
    #pragma unroll
    for (int nt = 0; nt < 4; ++nt)
      bf[nt] = *(const short8*)(Wu + (size_t)(nBase + nt * 16 + r16) * kH + k0);
    #pragma unroll
    for (int mt = 0; mt < 4; ++mt)
      #pragma unroll
      for (int nt = 0; nt < 4; ++nt)
        acc[mt][nt] = __builtin_amdgcn_mfma_f32_16x16x32_bf16(
            af[mt], bf[nt], acc[mt][nt], 0, 0, 0);
  }
  float bo[4];
  #pragma unroll
  for (int nt = 0; nt < 4; ++nt) bo[nt] = bout[nBase + nt * 16 + r16];
  #pragma unroll
  for (int mt = 0; mt < 4; ++mt) {
    #pragma unroll
    for (int r = 0; r < 4; ++r) {
      int row = mBase + mt * 16 + quad * 4 + r;
      float s = 0.f;
      #pragma unroll
      for (int nt = 0; nt < 4; ++nt) {
        float p = __expf(acc[mt][nt][r] + bo[nt]);
        out[(size_t)row * kV + nBase + nt * 16 + r16] = p;
        s += p;
      }
      s += __shfl_xor(s, 1);
      s += __shfl_xor(s, 2);
      s += __shfl_xor(s, 4);
      s += __shfl_xor(s, 8);
      if (r16 == 0) atomicAdd(&rowsum[row], s);
    }
  }
}

// ---------------------------------------------------------------------- K6
__global__ void k_scale(float* __restrict__ out, const float* __restrict__ rowsum) {
  const unsigned total4 = (unsigned)(kT * kB) * (kV / 4);
  unsigned stride = gridDim.x * blockDim.x;
  for (unsigned i = blockIdx.x * blockDim.x + threadIdx.x; i < total4; i += stride) {
    unsigned row = i / (kV / 4);
    float inv = 1.0f / rowsum[row];
    f4 v = ((const f4*)out)[i];
    ((f4*)out)[i] = v * inv;
  }
}

// ---------------------------------------------------------------------------
extern "C" void kernel_launch(void* const* d_in, const int* in_sizes, int n_in,
                              void* d_out, int out_size, void* d_ws, size_t ws_size,
                              hipStream_t stream) {
  (void)in_sizes; (void)n_in; (void)out_size; (void)ws_size;
  const int*   inputs  = (const int*)d_in[0];
  const float* hiddens = (const float*)d_in[1];
  const int*   tseq    = (const int*)d_in[2];
  const float* emb  = (const float*)d_in[4];
  const float* Wih1 = (const float*)d_in[5];
  const float* Whh1 = (const float*)d_in[6];
  const float* bih1 = (const float*)d_in[7];
  const float* bhh1 = (const float*)d_in[8];
  const float* Wih2 = (const float*)d_in[9];
  const float* Whh2 = (const float*)d_in[10];
  const float* bih2 = (const float*)d_in[11];
  const float* bhh2 = (const float*)d_in[12];
  const float* Wout = (const float*)d_in[13];
  const float* bout = (const float*)d_in[14];

  // workspace layout (float offsets); ~52 MiB
  float* ws = (float*)d_ws;
  float* Xg1T = ws;                                        //  4,194,304 f
  float* buf1 = ws + 4194304;                              //  2 x 16384 f
  float* buf2 = ws + 4227072;                              //  2 x 16384 f
  unsigned short* H2u = (unsigned short*)(ws + 4259840);   //  1,048,576 bf16
  unsigned short* Wu  = (unsigned short*)(ws + 4784128);   // 16,384,000 bf16
  float* rowsum = ws + 12976128;                           //  2048 f
  int* flags = (int*)(ws + 12978176);                      //  512 ints (A|B)
  int* flagsA = flags;
  int* flagsB = flags + 256;

  float* out = (float*)d_out;
  float* outTail = out + (size_t)kT * kB * kV;             // final h1 (32x512)

  hipLaunchKernelGGL(k_init, dim3(32), dim3(256), 0, stream, buf2, rowsum, flags);
  hipLaunchKernelGGL(k_wcvt, dim3(1024), dim3(256), 0, stream, Wout, Wu);
  hipLaunchKernelGGL(k_xg1, dim3(64, 32), dim3(256), 0, stream,
                     inputs, tseq, emb, Wih1, bih1, bhh1, Xg1T);
  hipLaunchKernelGGL(k_serial, dim3(kNWG), dim3(256), 0, stream,
                     hiddens, Xg1T, Whh1, Wih2, Whh2, bih2, bhh2,
                     buf1, buf2, H2u, outTail, flagsA, flagsB);
  hipLaunchKernelGGL(k_vocab, dim3(kV / 128, 16), dim3(256), 0, stream,
                     H2u, Wu, bout, out, rowsum);
  hipLaunchKernelGGL(k_scale, dim3(2048), dim3(256), 0, stream, out, rowsum);
}

// Round 2
// 2280.081 us; speedup vs baseline: 2.0401x; 1.9067x over previous
//
#include <hip/hip_runtime.h>
#include <stdint.h>

// ---------------------------------------------------------------------------
// DecoderRnn: 2-layer LSTM (B=32, H=512) over T=64 steps + vocab softmax (V=32000)
//   K1 k_init  : zero h2 double-buffer, rowsum, barrier counters
//   K2 k_wcvt  : W_out f32 -> bf16 for MFMA
//   K3 k_xg1   : Xg1T[t][j][b] = emb(x_t)@W_ih1^T + b_ih1 + b_hh1   (f32)
//   K4 k_serial: 64-step recurrence, 256 persistent WGs (1/CU).
//                Round-3 changes:
//                (a) counter barrier, SINGLE poller per WG: previous design had
//                    all 65536 threads spin-polling uncached flag loads ->
//                    multi-TB/s of garbage fabric traffic congesting the very
//                    stores the barrier waits on. Now: 1 atomicAdd/WG/phase on
//                    a monotonic counter, thread 0 polls one line, syncthreads.
//                (b) weights LDS-resident: each WG preloads its 24 weight rows
//                    (Whh1/Whh2/Wih2, 48 KB, row stride 516 f = +16B pad so the
//                    8 jj-rows hit disjoint bank quads; b-sharing lanes
//                    broadcast). GEMVs are now pure LDS+VALU - zero global
//                    loads in the hot loop (no exposed L2 latency at
//                    1 wave/SIMD, no fabric contention).
//                Cross-WG h exchange via relaxed agent-scope u64 atomics
//                (L3-coherent). Gate combine via in-wave shuffles.
//   K5 k_vocab : unnormalized probs = exp(H2@W_out^T + b_out), bf16 MFMA
//   K6 k_scale : probs /= rowsum
// ---------------------------------------------------------------------------

constexpr int kH = 512;
constexpr int kB = 32;
constexpr int kT = 64;
constexpr int kV = 32000;
constexpr int kG = 2048;   // 4*kH gates
constexpr int kNWG = 256;  // serial-kernel workgroups (1 per CU)
constexpr int kWS = 129;   // weight LDS row stride in f4 (516 floats = +16B pad)

typedef __attribute__((ext_vector_type(4))) float f4;
typedef __attribute__((ext_vector_type(8))) short short8;
typedef unsigned long long u64;

struct us4 { unsigned short x, y, z, w; };

__device__ inline unsigned short f2bf(float x) {
  union { float f; unsigned u; } c; c.f = x;
  unsigned r = c.u + 0x7fffu + ((c.u >> 16) & 1u);   // RNE to bf16
  return (unsigned short)(r >> 16);
}
__device__ inline float sigm(float x) { return 1.0f / (1.0f + expf(-x)); }

// ---------------------------------------------------------------------- K1
__global__ void k_init(float* __restrict__ buf2, float* __restrict__ rowsum,
                       int* __restrict__ flags /* 512 ints */) {
  int id = blockIdx.x * 256 + threadIdx.x;
  f4 z = {0.f, 0.f, 0.f, 0.f};
  if (id < 8192) ((f4*)buf2)[id] = z;       // both h2 buffers = 0
  if (id < 2048) rowsum[id] = 0.f;
  if (id < 512)  flags[id] = 0;
}

// ---------------------------------------------------------------------- K2
__global__ void k_wcvt(const float* __restrict__ W, unsigned short* __restrict__ Wu) {
  const int total = kV * kH / 4;
  for (int i = blockIdx.x * blockDim.x + threadIdx.x; i < total;
       i += gridDim.x * blockDim.x) {
    f4 v = ((const f4*)W)[i];
    us4 o = {f2bf(v.x), f2bf(v.y), f2bf(v.z), f2bf(v.w)};
    ((us4*)Wu)[i] = o;
  }
}

// ---------------------------------------------------------------------- K3
__global__ __launch_bounds__(256) void k_xg1(
    const int* __restrict__ inputs, const int* __restrict__ tseq,
    const float* __restrict__ emb, const float* __restrict__ Wih1,
    const float* __restrict__ bih1, const float* __restrict__ bhh1,
    float* __restrict__ Xg1T) {
  __shared__ float Xs[kB * kH];   // 64 KiB
  int tid = threadIdx.x;
  int t = blockIdx.x, jb = blockIdx.y;
  for (int i = tid; i < kB * kH / 4; i += 256) {
    int b = i >> 7;
    int tok = (t == 0) ? inputs[b] : tseq[b * kT + (t - 1)];
    ((f4*)Xs)[i] = ((const f4*)(emb + (size_t)tok * kH))[i & 127];
  }
  __syncthreads();
  int j2 = tid & 31, bq = tid >> 5;
  int j0 = jb * 64 + j2 * 2;
  int b0 = bq * 4;
  const f4* w0 = (const f4*)(Wih1 + (size_t)j0 * kH);
  const f4* w1 = (const f4*)(Wih1 + (size_t)(j0 + 1) * kH);
  float acc0[4] = {0.f, 0.f, 0.f, 0.f};
  float acc1[4] = {0.f, 0.f, 0.f, 0.f};
  #pragma unroll 2
  for (int k4 = 0; k4 < 128; ++k4) {
    f4 a0 = w0[k4], a1 = w1[k4];
    #pragma unroll
    for (int bb = 0; bb < 4; ++bb) {
      f4 x = ((const f4*)Xs)[(b0 + bb) * 128 + k4];
      acc0[bb] += a0.x * x.x + a0.y * x.y + a0.z * x.z + a0.w * x.w;
      acc1[bb] += a1.x * x.x + a1.y * x.y + a1.z * x.z + a1.w * x.w;
    }
  }
  float bj0 = bih1[j0] + bhh1[j0];
  float bj1 = bih1[j0 + 1] + bhh1[j0 + 1];
  f4 s0 = {acc0[0] + bj0, acc0[1] + bj0, acc0[2] + bj0, acc0[3] + bj0};
  f4 s1 = {acc1[0] + bj1, acc1[1] + bj1, acc1[2] + bj1, acc1[3] + bj1};
  float* o = Xg1T + ((size_t)t * kG + j0) * kB + b0;
  *(f4*)o = s0;
  *(f4*)(o + kB) = s1;
}

// ---------------------------------------------------------------------- K4
// Counter barrier. Producer: __syncthreads drains vmcnt(0) in every wave (all
// sc1 data stores complete at the coherence point) before thread 0 issues one
// relaxed agent atomicAdd on a monotonic counter. Consumer: ONLY thread 0
// polls (one cache line), then __syncthreads orders the observation before
// the WG's data loads. No release/acquire -> no buffer_wbl2/inv.
__device__ inline void postc(int* cnt) {
  __syncthreads();
  if (threadIdx.x == 0)
    __hip_atomic_fetch_add(cnt, 1, __ATOMIC_RELAXED, __HIP_MEMORY_SCOPE_AGENT);
}
__device__ inline void waitc(int* cnt, int target) {
  if (threadIdx.x == 0) {
    while (__hip_atomic_load(cnt, __ATOMIC_RELAXED,
                             __HIP_MEMORY_SCOPE_AGENT) < target)
      __builtin_amdgcn_s_sleep(2);
  }
  __syncthreads();
}

// Stage 32x512 f32 h-state into LDS (f4 XOR-swizzle: the 8 b-rows a wave
// reads per ds_read_b128 land on disjoint bank quads). Coherent variant uses
// relaxed agent u64 loads (bypasses stale L1 / non-coherent per-XCD L2).
__device__ inline void stage_coh(float* __restrict__ smem, const float* src) {
  const u64* s8 = (const u64*)src;
  #pragma unroll
  for (int i = 0; i < 16; ++i) {
    int idx = threadIdx.x + (i << 8);          // f4 index 0..4095
    u64 lo = __hip_atomic_load((u64*)&s8[idx * 2], __ATOMIC_RELAXED,
                               __HIP_MEMORY_SCOPE_AGENT);
    u64 hi = __hip_atomic_load((u64*)&s8[idx * 2 + 1], __ATOMIC_RELAXED,
                               __HIP_MEMORY_SCOPE_AGENT);
    int b_ = idx >> 7, k4 = idx & 127;
    union { u64 u[2]; f4 v; } cv; cv.u[0] = lo; cv.u[1] = hi;
    ((f4*)smem)[(b_ << 7) + (k4 ^ (b_ & 7))] = cv.v;
  }
}
__device__ inline void stage_plain(float* __restrict__ smem,
                                   const float* __restrict__ src) {
  const f4* s4 = (const f4*)src;
  #pragma unroll
  for (int i = 0; i < 16; ++i) {
    int idx = threadIdx.x + (i << 8);
    int b_ = idx >> 7, k4 = idx & 127;
    ((f4*)smem)[(b_ << 7) + (k4 ^ (b_ & 7))] = s4[idx];
  }
}

__global__ __launch_bounds__(256) void k_serial(
    const float* __restrict__ hiddens, const float* __restrict__ Xg1T,
    const float* __restrict__ Whh1, const float* __restrict__ Wih2,
    const float* __restrict__ Whh2, const float* __restrict__ bih2,
    const float* __restrict__ bhh2,
    float* __restrict__ buf1, float* __restrict__ buf2,
    unsigned short* __restrict__ H2u, float* __restrict__ outTail,
    int* __restrict__ cntA, int* __restrict__ cntB) {
  __shared__ float smemh[kB * kH];      // 64 KiB h-state stage
  __shared__ float wlds[24 * 4 * kWS]; // 48.4 KiB weights: [m 0..2][jj 0..7] rows
  const int tid = threadIdx.x, w = blockIdx.x;
  const int lane = tid & 63;
  const int b = tid >> 3, jj = tid & 7, gg = jj >> 1, nl = jj & 1;
  const int n = (w << 1) + nl;      // this WG owns hidden columns {2w, 2w+1}
  const int j = (gg << 9) + n;      // gate row: gate*512 + n
  const float bias2 = bih2[j] + bhh2[j];
  const bool holder = (jj < 2);     // thread (b,nl) carries c-state for col n
  const int srcbase = (lane & 56) | (lane & 1);
  float c1 = 0.f, c2 = 0.f;
  const int boff = b << 7, bsw = b & 7;

  // ---- preload this WG's 24 weight rows into LDS (rows: m*8+jj, m=0:Whh1,
  //      1:Whh2, 2:Wih2), row stride kWS f4 so jj-rows hit disjoint banks ----
  {
    f4* wl = (f4*)wlds;
    #pragma unroll
    for (int i = 0; i < 12; ++i) {
      int idx = tid + (i << 8);                // 0..3071
      int row = idx >> 7, k4 = idx & 127;
      int m = row >> 3, jjr = row & 7;
      int jr = ((jjr >> 1) << 9) + (w << 1) + (jjr & 1);
      const float* src = (m == 0) ? Whh1 : (m == 1) ? Whh2 : Wih2;
      wl[row * kWS + k4] = ((const f4*)(src + (size_t)jr * kH))[k4];
    }
  }
  const f4* wl1  = (const f4*)wlds + (0 * 8 + jj) * kWS;  // Whh1 row j
  const f4* wl2b = (const f4*)wlds + (1 * 8 + jj) * kWS;  // Whh2 row j
  const f4* wl2a = (const f4*)wlds + (2 * 8 + jj) * kWS;  // Wih2 row j
  const f4* hsm  = (const f4*)smemh;

  stage_plain(smemh, hiddens);      // h1[-1]
  __syncthreads();
  for (int t = 0; t < kT; ++t) {
    float* h1w = buf1 + (t & 1) * 16384;
    float* h2w = buf2 + (t & 1) * 16384;
    const float* h2r = buf2 + ((t + 1) & 1) * 16384;   // h2[t-1]

    // ---- layer-1 gates: Whh1[j].h1[t-1] + Xg1T (x-term incl. biases) ----
    float xg = Xg1T[((size_t)t * kG + j) * kB + b];
    f4 acc = {0.f, 0.f, 0.f, 0.f};
    #pragma unroll 8
    for (int k4 = 0; k4 < 128; ++k4)
      acc += wl1[k4] * hsm[boff + (k4 ^ bsw)];
    float g1v = acc.x + acc.y + acc.z + acc.w + xg;
    // in-wave gate combine (gates i,f,g,o for col n are at jj = nl,2+nl,4+nl,6+nl)
    float gi = __shfl(g1v, srcbase);
    float gf = __shfl(g1v, srcbase + 2);
    float gG = __shfl(g1v, srcbase + 4);
    float go = __shfl(g1v, srcbase + 6);
    float hnew = 0.f;
    if (holder) {
      float i_ = sigm(gi), f_ = sigm(gf), G_ = tanhf(gG), o_ = sigm(go);
      c1 = f_ * c1 + i_ * G_;
      hnew = o_ * tanhf(c1);
    }
    float hp = __shfl(hnew, lane + 1);
    if (jj == 0) {
      union { float f[2]; u64 u; } pk; pk.f[0] = hnew; pk.f[1] = hp;
      __hip_atomic_store((u64*)(h1w + b * kH + 2 * w), pk.u, __ATOMIC_RELAXED,
                         __HIP_MEMORY_SCOPE_AGENT);
      if (t == kT - 1) *(u64*)(outTail + b * kH + 2 * w) = pk.u;  // output 1
    }
    postc(cntA);                    // publish h1[t] (syncthreads drains stores)
    waitc(cntB, 256 * t);           // h2[t-1] visible from all WGs

    stage_coh(smemh, h2r);          // h2[t-1]
    __syncthreads();
    // ---- layer-2 partial: Whh2[j].h2[t-1] (overlaps other WGs' A-posts) ----
    f4 a2 = {0.f, 0.f, 0.f, 0.f};
    #pragma unroll 8
    for (int k4 = 0; k4 < 128; ++k4)
      a2 += wl2b[k4] * hsm[boff + (k4 ^ bsw)];
    waitc(cntA, 256 * (t + 1));     // h1[t] visible from all WGs

    stage_coh(smemh, h1w);          // h1[t] (stays staged for next step's layer-1)
    __syncthreads();
    #pragma unroll 8
    for (int k4 = 0; k4 < 128; ++k4)
      a2 += wl2a[k4] * hsm[boff + (k4 ^ bsw)];
    float g2v = a2.x + a2.y + a2.z + a2.w + bias2;
    float g2i = __shfl(g2v, srcbase);
    float g2f = __shfl(g2v, srcbase + 2);
    float g2G = __shfl(g2v, srcbase + 4);
    float g2o = __shfl(g2v, srcbase + 6);
    float h2new = 0.f;
    if (holder) {
      float i_ = sigm(g2i), f_ = sigm(g2f), G_ = tanhf(g2G), o_ = sigm(g2o);
      c2 = f_ * c2 + i_ * G_;
      h2new = o_ * tanhf(c2);
    }
    float h2p = __shfl(h2new, lane + 1);
    if (jj == 0) {
      union { float f[2]; u64 u; } pk; pk.f[0] = h2new; pk.f[1] = h2p;
      __hip_atomic_store((u64*)(h2w + b * kH + 2 * w), pk.u, __ATOMIC_RELAXED,
                         __HIP_MEMORY_SCOPE_AGENT);
      unsigned bf2 = ((unsigned)f2bf(h2p) << 16) | f2bf(h2new);
      *(unsigned*)(H2u + ((size_t)t * kB + b) * kH + 2 * w) = bf2;  // bf16 pair
    }
    postc(cntB);                    // publish h2[t]
    // smemh still holds h1[t] -> next iteration's layer-1 needs no restage
  }
}

// ---------------------------------------------------------------------- K5
__global__ __launch_bounds__(256) void k_vocab(
    const unsigned short* __restrict__ H2u, const unsigned short* __restrict__ Wu,
    const float* __restrict__ bout, float* __restrict__ out,
    float* __restrict__ rowsum) {
  const int lane = threadIdx.x & 63, wv = threadIdx.x >> 6;
  const int wm = wv >> 1, wn = wv & 1;
  const int r16 = lane & 15, quad = lane >> 4;
  const int mBase = blockIdx.y * 128 + wm * 64;
  const int nBase = blockIdx.x * 128 + wn * 64;
  f4 acc[4][4];
  #pragma unroll
  for (int a = 0; a < 4; ++a)
    #pragma unroll
    for (int c = 0; c < 4; ++c) acc[a][c] = (f4){0.f, 0.f, 0.f, 0.f};
  for (int kb = 0; kb < 16; ++kb) {
    int k0 = kb * 32 + quad * 8;
    short8 af[4], bf[4];
    #pragma unroll
    for (int mt = 0; mt < 4; ++mt)
      af[mt] = *(const short8*)(H2u + (size_t)(mBase + mt * 16 + r16) * kH + k0);
    #pragma unroll
    for (int nt = 0; nt < 4; ++nt)
      bf[nt] = *(const short8*)(Wu + (size_t)(nBase + nt * 16 + r16) * kH + k0);
    #pragma unroll
    for (int mt = 0; mt < 4; ++mt)
      #pragma unroll
      for (int nt = 0; nt < 4; ++nt)
        acc[mt][nt] = __builtin_amdgcn_mfma_f32_16x16x32_bf16(
            af[mt], bf[nt], acc[mt][nt], 0, 0, 0);
  }
  float bo[4];
  #pragma unroll
  for (int nt = 0; nt < 4; ++nt) bo[nt] = bout[nBase + nt * 16 + r16];
  #pragma unroll
  for (int mt = 0; mt < 4; ++mt) {
    #pragma unroll
    for (int r = 0; r < 4; ++r) {
      int row = mBase + mt * 16 + quad * 4 + r;
      float s = 0.f;
      #pragma unroll
      for (int nt = 0; nt < 4; ++nt) {
        float p = __expf(acc[mt][nt][r] + bo[nt]);
        out[(size_t)row * kV + nBase + nt * 16 + r16] = p;
        s += p;
      }
      s += __shfl_xor(s, 1);
      s += __shfl_xor(s, 2);
      s += __shfl_xor(s, 4);
      s += __shfl_xor(s, 8);
      if (r16 == 0) atomicAdd(&rowsum[row], s);
    }
  }
}

// ---------------------------------------------------------------------- K6
__global__ void k_scale(float* __restrict__ out, const float* __restrict__ rowsum) {
  const unsigned total4 = (unsigned)(kT * kB) * (kV / 4);
  unsigned stride = gridDim.x * blockDim.x;
  for (unsigned i = blockIdx.x * blockDim.x + threadIdx.x; i < total4; i += stride) {
    unsigned row = i / (kV / 4);
    float inv = 1.0f / rowsum[row];
    f4 v = ((const f4*)out)[i];
    ((f4*)out)[i] = v * inv;
  }
}

// ---------------------------------------------------------------------------
extern "C" void kernel_launch(void* const* d_in, const int* in_sizes, int n_in,
                              void* d_out, int out_size, void* d_ws, size_t ws_size,
                              hipStream_t stream) {
  (void)in_sizes; (void)n_in; (void)out_size; (void)ws_size;
  const int*   inputs  = (const int*)d_in[0];
  const float* hiddens = (const float*)d_in[1];
  const int*   tseq    = (const int*)d_in[2];
  const float* emb  = (const float*)d_in[4];
  const float* Wih1 = (const float*)d_in[5];
  const float* Whh1 = (const float*)d_in[6];
  const float* bih1 = (const float*)d_in[7];
  const float* bhh1 = (const float*)d_in[8];
  const float* Wih2 = (const float*)d_in[9];
  const float* Whh2 = (const float*)d_in[10];
  const float* bih2 = (const float*)d_in[11];
  const float* bhh2 = (const float*)d_in[12];
  const float* Wout = (const float*)d_in[13];
  const float* bout = (const float*)d_in[14];

  // workspace layout (float offsets); ~52 MiB
  float* ws = (float*)d_ws;
  float* Xg1T = ws;                                        //  4,194,304 f
  float* buf1 = ws + 4194304;                              //  2 x 16384 f
  float* buf2 = ws + 4227072;                              //  2 x 16384 f
  unsigned short* H2u = (unsigned short*)(ws + 4259840);   //  1,048,576 bf16
  unsigned short* Wu  = (unsigned short*)(ws + 4784128);   // 16,384,000 bf16
  float* rowsum = ws + 12976128;                           //  2048 f
  int* flags = (int*)(ws + 12978176);                      //  512 ints
  int* cntA = flags;                                       //  monotonic counters
  int* cntB = flags + 16;                                  //  (separate lines)

  float* out = (float*)d_out;
  float* outTail = out + (size_t)kT * kB * kV;             // final h1 (32x512)

  hipLaunchKernelGGL(k_init, dim3(32), dim3(256), 0, stream, buf2, rowsum, flags);
  hipLaunchKernelGGL(k_wcvt, dim3(1024), dim3(256), 0, stream, Wout, Wu);
  hipLaunchKernelGGL(k_xg1, dim3(64, 32), dim3(256), 0, stream,
                     inputs, tseq, emb, Wih1, bih1, bhh1, Xg1T);
  hipLaunchKernelGGL(k_serial, dim3(kNWG), dim3(256), 0, stream,
                     hiddens, Xg1T, Whh1, Wih2, Whh2, bih2, bhh2,
                     buf1, buf2, H2u, outTail, cntA, cntB);
  hipLaunchKernelGGL(k_vocab, dim3(kV / 128, 16), dim3(256), 0, stream,
                     H2u, Wu, bout, out, rowsum);
  hipLaunchKernelGGL(k_scale, dim3(2048), dim3(256), 0, stream, out, rowsum);
}